// Round 4
// baseline (264.350 us; speedup 1.0000x reference)
//
#include <hip/hip_runtime.h>
#include <cstdint>

#define B_   8
#define C_   256
#define H_   64
#define W_   64
#define HW_  4096
#define NH_  8
#define NP_  4
#define DH_  32

typedef unsigned int u32;
typedef unsigned short u16;
typedef __attribute__((ext_vector_type(8))) short bf16x8;
typedef __attribute__((ext_vector_type(4))) float f32x4;
typedef __attribute__((ext_vector_type(4))) u32 u32x4;
typedef __attribute__((address_space(3))) u32 as3_u32;
typedef __attribute__((address_space(1))) u32 as1_u32;

__device__ __forceinline__ u16 f2bf(float f) {
  u32 u = __builtin_bit_cast(u32, f);
  return (u16)((u + 0x7FFFu + ((u >> 16) & 1u)) >> 16);
}
__device__ __forceinline__ float bflo(u32 v) { return __builtin_bit_cast(float, v << 16); }
__device__ __forceinline__ float bfhi(u32 v) { return __builtin_bit_cast(float, v & 0xFFFF0000u); }

// ---------------------------------------------------------------------------
// Kernel 1: merged prep. blocks [0,4096): key transpose->bf16;
// [4096,4352): offsets MFMA GEMM + softmax -> params; [4352,4416): w_proj->bf16.
// ---------------------------------------------------------------------------
__global__ __launch_bounds__(256) void k_prep(const float* __restrict__ query,
                                              const float* __restrict__ key,
                                              const float* __restrict__ w_off,
                                              const float* __restrict__ b_off,
                                              const float* __restrict__ w_proj,
                                              float4* __restrict__ params,
                                              u32* __restrict__ key_t2,
                                              uint2* __restrict__ wproj_bf) {
  __shared__ char smem[57344];
  const int bid = blockIdx.x;
  const int t = threadIdx.x;

  if (bid < 4096) {
    // ---- transpose key (G, DH, HW) -> key_t2 (G, HW, 16 u32) ----
    float* tile = (float*)smem;  // 32 x 65
    const int g = bid >> 6;
    const int hw0 = (bid & 63) << 6;
    const float* kg = key + (size_t)g * DH_ * HW_ + hw0;
    #pragma unroll
    for (int k = 0; k < 8; ++k) {
      int idx = t + k * 256;
      int d = idx >> 6, j = idx & 63;
      tile[d * 65 + j] = kg[d * HW_ + j];
    }
    __syncthreads();
    u32* kt = key_t2 + ((size_t)g * HW_ + hw0) * 16;
    #pragma unroll
    for (int k = 0; k < 4; ++k) {
      int idx = t + k * 256;
      int j = idx >> 4, dp = idx & 15;
      u32 v = (u32)f2bf(tile[(2 * dp) * 65 + j]) | ((u32)f2bf(tile[(2 * dp + 1) * 65 + j]) << 16);
      kt[j * 16 + dp] = v;
    }
  } else if (bid < 4352) {
    // ---- offsets GEMM (bf16 MFMA) + softmax epilogue ----
    const int l = t & 63, w = t >> 6;
    const int lr = l & 15, lq = l >> 4;
    const int r0 = (bid - 4096) * 128;
    const int b  = r0 >> 12;
    const int hw0 = r0 & 4095;

    {
      const float4* w4 = (const float4*)w_off;
      #pragma unroll
      for (int j = 0; j < 12; ++j) {
        int m = t + j * 256;
        int col = m >> 5, ch = m & 31;
        float4 lo = w4[m * 2];
        float4 hi = w4[m * 2 + 1];
        u32x4 v;
        v.x = (u32)f2bf(lo.x) | ((u32)f2bf(lo.y) << 16);
        v.y = (u32)f2bf(lo.z) | ((u32)f2bf(lo.w) << 16);
        v.z = (u32)f2bf(hi.x) | ((u32)f2bf(hi.y) << 16);
        v.w = (u32)f2bf(hi.z) | ((u32)f2bf(hi.w) << 16);
        int slot = (col << 5) | (ch ^ (col & 7));
        *(u32x4*)(smem + slot * 16) = v;
      }
    }

    f32x4 acc[2][6];
    #pragma unroll
    for (int m = 0; m < 2; ++m)
      #pragma unroll
      for (int n = 0; n < 6; ++n)
        acc[m][n] = (f32x4){0.f, 0.f, 0.f, 0.f};

    for (int step = 0; step < 8; ++step) {
      const int k0 = step * 32;
      #pragma unroll
      for (int it = 0; it < 8; ++it) {
        int idx = t + it * 256;
        int i = idx & 127;
        int p = idx >> 7;
        const float* src = query + ((size_t)(b * 256 + k0 + 2 * p)) * 4096 + hw0 + i;
        u32 v = (u32)f2bf(src[0]) | ((u32)f2bf(src[4096]) << 16);
        *(u32*)(smem + 49152 + ((p >> 2) * 128 + i) * 16 + (p & 3) * 4) = v;
      }
      __syncthreads();

      const int chb = step * 4 + lq;
      bf16x8 bfr[6], af[2];
      #pragma unroll
      for (int n = 0; n < 6; ++n) {
        int col = n * 16 + lr;
        bfr[n] = *(const bf16x8*)(smem + ((col << 5) | (chb ^ (col & 7))) * 16);
      }
      #pragma unroll
      for (int m = 0; m < 2; ++m)
        af[m] = *(const bf16x8*)(smem + 49152 + (lq * 128 + w * 32 + m * 16 + lr) * 16);

      #pragma unroll
      for (int m = 0; m < 2; ++m)
        #pragma unroll
        for (int n = 0; n < 6; ++n)
          acc[m][n] = __builtin_amdgcn_mfma_f32_16x16x32_bf16(af[m], bfr[n], acc[m][n], 0, 0, 0);
      __syncthreads();
    }

    float* epi = (float*)smem;
    #pragma unroll
    for (int n = 0; n < 6; ++n) {
      int o = n * 16 + lr;
      float bo = b_off[o];
      #pragma unroll
      for (int m = 0; m < 2; ++m) {
        int row = w * 32 + m * 16 + lq * 4;
        #pragma unroll
        for (int r = 0; r < 4; ++r)
          epi[(row + r) * 98 + o] = acc[m][n][r] + bo;
      }
    }
    __syncthreads();

    #pragma unroll
    for (int k = 0; k < 4; ++k) {
      int task = t + k * 256;
      int row = task & 127, head = task >> 7;
      const float* o = epi + row * 98 + head * 12;
      float ox[NP_], oy[NP_], lg[NP_];
      #pragma unroll
      for (int p = 0; p < NP_; ++p) {
        ox[p] = o[p * 3 + 0];
        oy[p] = o[p * 3 + 1];
        lg[p] = o[p * 3 + 2];
      }
      float mx = fmaxf(fmaxf(lg[0], lg[1]), fmaxf(lg[2], lg[3]));
      float e[NP_];
      float s = 0.f;
      #pragma unroll
      for (int p = 0; p < NP_; ++p) { e[p] = expf(lg[p] - mx); s += e[p]; }
      float inv = 1.f / s;

      int hw = (r0 + row) & 4095;
      float wq = (float)(hw & 63);
      float hq = (float)(hw >> 6);
      float4* dst = params + ((size_t)(b * NH_ + head) * HW_ + hw) * NP_;
      #pragma unroll
      for (int p = 0; p < NP_; ++p) {
        dst[p] = make_float4(wq + ox[p] * 3.15f, hq + oy[p] * 3.15f, e[p] * inv, 0.f);
      }
    }
  } else {
    // ---- convert w_proj to bf16 pairs ----
    int i = (bid - 4352) * 256 + t;
    float4 v = ((const float4*)w_proj)[i];
    uint2 o;
    o.x = (u32)f2bf(v.x) | ((u32)f2bf(v.y) << 16);
    o.y = (u32)f2bf(v.z) | ((u32)f2bf(v.w) << 16);
    wproj_bf[i] = o;
  }
}

// ---------------------------------------------------------------------------
// Kernel 2: fused sample + projection.
// Block = 64 output rows (one b, 64 hw). Phase 1: bilinear-sample feat tile
// (64 x 256 bf16) into LDS in MFMA A layout [kc 0..31][row 0..63] 16B slots.
// Phase 2: GEMM vs w_proj^T (bf16 MFMA, B staged per 32-K chunk), + bias.
// ---------------------------------------------------------------------------
__global__ __launch_bounds__(256) void k_fused(const float4* __restrict__ params,
                                               const u32* __restrict__ key_t2,
                                               const u16* __restrict__ Bw,
                                               const float* __restrict__ bias,
                                               float* __restrict__ out) {
  __shared__ char smem[49152];  // A: [0,32K)  B-chunk: [32K,48K)
  const int t = threadIdx.x, l = t & 63, w = t >> 6;
  const int lr = l & 15, lq = l >> 4;
  const int r0 = blockIdx.x * 64;
  const int b = r0 >> 12;
  const int hw0 = r0 & 4095;

  // ---- Phase 1: sampling ----
  {
    const int row = t & 63;
    const int hw = hw0 + row;
    const int cbase = t >> 6;          // 0..3
    const float wqf = (float)(hw & 63);
    const float hqf = (float)(hw >> 6);
    (void)wqf; (void)hqf;
    #pragma unroll 2
    for (int it = 0; it < 32; ++it) {
      int c2 = cbase * 32 + it;        // 0..127
      int head = c2 >> 4, dp = c2 & 15;
      int g = b * NH_ + head;
      const float4* pp = params + (((size_t)g << 12) + hw) * NP_;
      const u32* kg = key_t2 + ((size_t)g << 16) + dp;

      float a0 = 0.f, a1 = 0.f;
      #pragma unroll
      for (int p = 0; p < NP_; ++p) {
        float4 pr = pp[p];
        float x = pr.x, y = pr.y, wt = pr.z;
        float x0f = floorf(x), y0f = floorf(y);
        int ix0 = (int)x0f, iy0 = (int)y0f;
        int ix1 = ix0 + 1, iy1 = iy0 + 1;
        float fx = x - x0f, fy = y - y0f;
        float gx0 = 1.f - fx, gy0 = 1.f - fy;

        bool vx0 = (ix0 >= 0) & (ix0 <= W_ - 1);
        bool vx1 = (ix1 >= 0) & (ix1 <= W_ - 1);
        bool vy0 = (iy0 >= 0) & (iy0 <= H_ - 1);
        bool vy1 = (iy1 >= 0) & (iy1 <= H_ - 1);
        int cx0 = min(max(ix0, 0), W_ - 1), cx1 = min(max(ix1, 0), W_ - 1);
        int cy0 = min(max(iy0, 0), H_ - 1), cy1 = min(max(iy1, 0), H_ - 1);

        u32 v00 = kg[(cy0 * W_ + cx0) * 16];
        u32 v01 = kg[(cy0 * W_ + cx1) * 16];
        u32 v10 = kg[(cy1 * W_ + cx0) * 16];
        u32 v11 = kg[(cy1 * W_ + cx1) * 16];

        float w00 = gx0 * gy0 * ((vx0 & vy0) ? 1.f : 0.f);
        float w01 = fx  * gy0 * ((vx1 & vy0) ? 1.f : 0.f);
        float w10 = gx0 * fy  * ((vx0 & vy1) ? 1.f : 0.f);
        float w11 = fx  * fy  * ((vx1 & vy1) ? 1.f : 0.f);

        a0 = fmaf(wt, w00 * bflo(v00) + w01 * bflo(v01) + w10 * bflo(v10) + w11 * bflo(v11), a0);
        a1 = fmaf(wt, w00 * bfhi(v00) + w01 * bfhi(v01) + w10 * bfhi(v10) + w11 * bfhi(v11), a1);
      }
      // channel pair c = 2*c2, 2*c2+1 -> slot kc = c>>3 = head*4 + (dp>>2), word = dp&3
      int kc = head * 4 + (dp >> 2);
      *(u32*)(smem + (kc * 64 + row) * 16 + (dp & 3) * 4) =
          (u32)f2bf(a0) | ((u32)f2bf(a1) << 16);
    }
  }

  // ---- Phase 2: GEMM (64 x 256) = A(64x256) * w_proj^T(256x256) ----
  f32x4 acc[16];
  #pragma unroll
  for (int n = 0; n < 16; ++n) acc[n] = (f32x4){0.f, 0.f, 0.f, 0.f};

  for (int k0 = 0; k0 < 256; k0 += 32) {
    // stage B chunk: slots [kq 0..3][col 0..255], 16 x 1KB issues, 4/wave
    #pragma unroll
    for (int j = 0; j < 4; ++j) {
      int i = w * 4 + j;               // 0..15
      int kq = i >> 2, cg = i & 3;
      const u16* gsrc = Bw + ((size_t)(cg * 64 + l)) * 256 + k0 + kq * 8;
      __builtin_amdgcn_global_load_lds((const as1_u32*)gsrc,
          (as3_u32*)(smem + 32768 + (kq * 256 + cg * 64) * 16), 16, 0, 0);
    }
    __syncthreads();  // drains vmcnt; also guards phase-1 A writes on first pass

    const int kc = (k0 >> 3) + lq;
    bf16x8 af = *(const bf16x8*)(smem + (kc * 64 + w * 16 + lr) * 16);
    #pragma unroll
    for (int n = 0; n < 16; ++n) {
      bf16x8 bfr = *(const bf16x8*)(smem + 32768 + (lq * 256 + n * 16 + lr) * 16);
      acc[n] = __builtin_amdgcn_mfma_f32_16x16x32_bf16(af, bfr, acc[n], 0, 0, 0);
    }
    __syncthreads();  // before overwriting B chunk
  }

  // ---- epilogue ----
  #pragma unroll
  for (int n = 0; n < 16; ++n) {
    int col = n * 16 + lr;
    float bv = bias[col];
    int row = r0 + w * 16 + lq * 4;
    #pragma unroll
    for (int r = 0; r < 4; ++r)
      out[(size_t)(row + r) * 256 + col] = acc[n][r] + bv;
  }
}

// ---------------------------------------------------------------------------
extern "C" void kernel_launch(void* const* d_in, const int* in_sizes, int n_in,
                              void* d_out, int out_size, void* d_ws, size_t ws_size,
                              hipStream_t stream) {
  const float* query  = (const float*)d_in[0];
  const float* key    = (const float*)d_in[1];
  const float* w_off  = (const float*)d_in[2];
  const float* b_off  = (const float*)d_in[3];
  const float* w_proj = (const float*)d_in[4];
  const float* b_proj = (const float*)d_in[5];
  float* out = (float*)d_out;

  char* ws = (char*)d_ws;
  float4* params   = (float4*)ws;                               // 16 MB
  u32*    key_t2   = (u32*)(ws + (size_t)16 * 1024 * 1024);     // 16 MB
  uint2*  wproj_bf = (uint2*)(ws + (size_t)32 * 1024 * 1024);   // 128 KB

  hipLaunchKernelGGL(k_prep,  dim3(4416), dim3(256), 0, stream,
                     query, key, w_off, b_off, w_proj, params, key_t2, wproj_bf);
  hipLaunchKernelGGL(k_fused, dim3(512),  dim3(256), 0, stream,
                     params, key_t2, (const u16*)wproj_bf, b_proj, out);
}

// Round 5
// 92.110 us; speedup vs baseline: 2.8699x; 2.8699x over previous
//
#include <hip/hip_runtime.h>
#include <cstdint>

#define B_   8
#define C_   256
#define H_   64
#define W_   64
#define HW_  4096
#define NH_  8
#define NP_  4
#define DH_  32

typedef unsigned int u32;
typedef unsigned short u16;
typedef __attribute__((ext_vector_type(8))) short bf16x8;
typedef __attribute__((ext_vector_type(4))) float f32x4;
typedef __attribute__((ext_vector_type(4))) u32 u32x4;
typedef __attribute__((address_space(3))) u32 as3_u32;
typedef __attribute__((address_space(1))) u32 as1_u32;

__device__ __forceinline__ u16 f2bf(float f) {
  u32 u = __builtin_bit_cast(u32, f);
  return (u16)((u + 0x7FFFu + ((u >> 16) & 1u)) >> 16);
}
__device__ __forceinline__ float bflo(u32 v) { return __builtin_bit_cast(float, v << 16); }
__device__ __forceinline__ float bfhi(u32 v) { return __builtin_bit_cast(float, v & 0xFFFF0000u); }

// ---------------------------------------------------------------------------
// Kernel 1: merged prep. blocks [0,4096): key transpose->bf16;
// [4096,4352): offsets MFMA GEMM + softmax -> params; [4352,4416): w_proj->bf16.
// ---------------------------------------------------------------------------
__global__ __launch_bounds__(256) void k_prep(const float* __restrict__ query,
                                              const float* __restrict__ key,
                                              const float* __restrict__ w_off,
                                              const float* __restrict__ b_off,
                                              const float* __restrict__ w_proj,
                                              float4* __restrict__ params,
                                              u32* __restrict__ key_t2,
                                              uint2* __restrict__ wproj_bf) {
  __shared__ char smem[57344];
  const int bid = blockIdx.x;
  const int t = threadIdx.x;

  if (bid < 4096) {
    // ---- transpose key (G, DH, HW) -> key_t2 (G, HW, 16 u32) ----
    float* tile = (float*)smem;  // 32 x 65
    const int g = bid >> 6;
    const int hw0 = (bid & 63) << 6;
    const float* kg = key + (size_t)g * DH_ * HW_ + hw0;
    #pragma unroll
    for (int k = 0; k < 8; ++k) {
      int idx = t + k * 256;
      int d = idx >> 6, j = idx & 63;
      tile[d * 65 + j] = kg[d * HW_ + j];
    }
    __syncthreads();
    u32* kt = key_t2 + ((size_t)g * HW_ + hw0) * 16;
    #pragma unroll
    for (int k = 0; k < 4; ++k) {
      int idx = t + k * 256;
      int j = idx >> 4, dp = idx & 15;
      u32 v = (u32)f2bf(tile[(2 * dp) * 65 + j]) | ((u32)f2bf(tile[(2 * dp + 1) * 65 + j]) << 16);
      kt[j * 16 + dp] = v;
    }
  } else if (bid < 4352) {
    // ---- offsets GEMM (bf16 MFMA) + softmax epilogue ----
    const int l = t & 63, w = t >> 6;
    const int lr = l & 15, lq = l >> 4;
    const int r0 = (bid - 4096) * 128;
    const int b  = r0 >> 12;
    const int hw0 = r0 & 4095;

    {
      const float4* w4 = (const float4*)w_off;
      #pragma unroll
      for (int j = 0; j < 12; ++j) {
        int m = t + j * 256;
        int col = m >> 5, ch = m & 31;
        float4 lo = w4[m * 2];
        float4 hi = w4[m * 2 + 1];
        u32x4 v;
        v.x = (u32)f2bf(lo.x) | ((u32)f2bf(lo.y) << 16);
        v.y = (u32)f2bf(lo.z) | ((u32)f2bf(lo.w) << 16);
        v.z = (u32)f2bf(hi.x) | ((u32)f2bf(hi.y) << 16);
        v.w = (u32)f2bf(hi.z) | ((u32)f2bf(hi.w) << 16);
        int slot = (col << 5) | (ch ^ (col & 7));
        *(u32x4*)(smem + slot * 16) = v;
      }
    }

    f32x4 acc[2][6];
    #pragma unroll
    for (int m = 0; m < 2; ++m)
      #pragma unroll
      for (int n = 0; n < 6; ++n)
        acc[m][n] = (f32x4){0.f, 0.f, 0.f, 0.f};

    for (int step = 0; step < 8; ++step) {
      const int k0 = step * 32;
      #pragma unroll
      for (int it = 0; it < 8; ++it) {
        int idx = t + it * 256;
        int i = idx & 127;
        int p = idx >> 7;
        const float* src = query + ((size_t)(b * 256 + k0 + 2 * p)) * 4096 + hw0 + i;
        u32 v = (u32)f2bf(src[0]) | ((u32)f2bf(src[4096]) << 16);
        *(u32*)(smem + 49152 + ((p >> 2) * 128 + i) * 16 + (p & 3) * 4) = v;
      }
      __syncthreads();

      const int chb = step * 4 + lq;
      bf16x8 bfr[6], af[2];
      #pragma unroll
      for (int n = 0; n < 6; ++n) {
        int col = n * 16 + lr;
        bfr[n] = *(const bf16x8*)(smem + ((col << 5) | (chb ^ (col & 7))) * 16);
      }
      #pragma unroll
      for (int m = 0; m < 2; ++m)
        af[m] = *(const bf16x8*)(smem + 49152 + (lq * 128 + w * 32 + m * 16 + lr) * 16);

      #pragma unroll
      for (int m = 0; m < 2; ++m)
        #pragma unroll
        for (int n = 0; n < 6; ++n)
          acc[m][n] = __builtin_amdgcn_mfma_f32_16x16x32_bf16(af[m], bfr[n], acc[m][n], 0, 0, 0);
      __syncthreads();
    }

    float* epi = (float*)smem;
    #pragma unroll
    for (int n = 0; n < 6; ++n) {
      int o = n * 16 + lr;
      float bo = b_off[o];
      #pragma unroll
      for (int m = 0; m < 2; ++m) {
        int row = w * 32 + m * 16 + lq * 4;
        #pragma unroll
        for (int r = 0; r < 4; ++r)
          epi[(row + r) * 98 + o] = acc[m][n][r] + bo;
      }
    }
    __syncthreads();

    #pragma unroll
    for (int k = 0; k < 4; ++k) {
      int task = t + k * 256;
      int row = task & 127, head = task >> 7;
      const float* o = epi + row * 98 + head * 12;
      float ox[NP_], oy[NP_], lg[NP_];
      #pragma unroll
      for (int p = 0; p < NP_; ++p) {
        ox[p] = o[p * 3 + 0];
        oy[p] = o[p * 3 + 1];
        lg[p] = o[p * 3 + 2];
      }
      float mx = fmaxf(fmaxf(lg[0], lg[1]), fmaxf(lg[2], lg[3]));
      float e[NP_];
      float s = 0.f;
      #pragma unroll
      for (int p = 0; p < NP_; ++p) { e[p] = expf(lg[p] - mx); s += e[p]; }
      float inv = 1.f / s;

      int hw = (r0 + row) & 4095;
      float wq = (float)(hw & 63);
      float hq = (float)(hw >> 6);
      float4* dst = params + ((size_t)(b * NH_ + head) * HW_ + hw) * NP_;
      #pragma unroll
      for (int p = 0; p < NP_; ++p) {
        dst[p] = make_float4(wq + ox[p] * 3.15f, hq + oy[p] * 3.15f, e[p] * inv, 0.f);
      }
    }
  } else {
    // ---- convert w_proj to bf16 pairs ----
    int i = (bid - 4352) * 256 + t;
    float4 v = ((const float4*)w_proj)[i];
    uint2 o;
    o.x = (u32)f2bf(v.x) | ((u32)f2bf(v.y) << 16);
    o.y = (u32)f2bf(v.z) | ((u32)f2bf(v.w) << 16);
    wproj_bf[i] = o;
  }
}

// ---------------------------------------------------------------------------
// Kernel 2: fused sample + projection.
// Block = 64 output rows (one b, 64 hw).
// Phase 1: bilinear-sample into LDS A layout [kc 0..31][row 0..63] 16B slots.
//   Lane mapping = validated k_sample order: dp = t&15 (consecutive lanes ->
//   consecutive u32 -> 64B coalesced gathers), head = (t>>4)&7, 2 rows/iter.
// Phase 2: GEMM vs w_proj^T (bf16 MFMA, B staged per 32-K chunk), + bias.
// ---------------------------------------------------------------------------
__global__ __launch_bounds__(256) void k_fused(const float4* __restrict__ params,
                                               const u32* __restrict__ key_t2,
                                               const u16* __restrict__ Bw,
                                               const float* __restrict__ bias,
                                               float* __restrict__ out) {
  __shared__ char smem[49152];  // A: [0,32K)  B-chunk: [32K,48K)
  const int t = threadIdx.x, l = t & 63, w = t >> 6;
  const int lr = l & 15, lq = l >> 4;
  const int r0 = blockIdx.x * 64;
  const int b = r0 >> 12;
  const int hw0 = r0 & 4095;

  // ---- Phase 1: sampling (coalesced dp-lane mapping) ----
  {
    const int dp   = t & 15;           // channel-pair within head
    const int head = (t >> 4) & 7;
    const int rsub = t >> 7;           // 0..1
    const int g = b * NH_ + head;
    const u32* kg = key_t2 + ((size_t)g << 16) + dp;
    const int kc = head * 4 + (dp >> 2);
    const int word = (dp & 3) * 4;

    #pragma unroll 4
    for (int it = 0; it < 32; ++it) {
      int row = it * 2 + rsub;
      int hw = hw0 + row;
      const float4* pp = params + (((size_t)g << 12) + hw) * NP_;

      float a0 = 0.f, a1 = 0.f;
      #pragma unroll
      for (int p = 0; p < NP_; ++p) {
        float4 pr = pp[p];
        float x = pr.x, y = pr.y, wt = pr.z;
        float x0f = floorf(x), y0f = floorf(y);
        int ix0 = (int)x0f, iy0 = (int)y0f;
        int ix1 = ix0 + 1, iy1 = iy0 + 1;
        float fx = x - x0f, fy = y - y0f;
        float gx0 = 1.f - fx, gy0 = 1.f - fy;

        bool vx0 = (ix0 >= 0) & (ix0 <= W_ - 1);
        bool vx1 = (ix1 >= 0) & (ix1 <= W_ - 1);
        bool vy0 = (iy0 >= 0) & (iy0 <= H_ - 1);
        bool vy1 = (iy1 >= 0) & (iy1 <= H_ - 1);
        int cx0 = min(max(ix0, 0), W_ - 1), cx1 = min(max(ix1, 0), W_ - 1);
        int cy0 = min(max(iy0, 0), H_ - 1), cy1 = min(max(iy1, 0), H_ - 1);

        u32 v00 = kg[(cy0 * W_ + cx0) * 16];
        u32 v01 = kg[(cy0 * W_ + cx1) * 16];
        u32 v10 = kg[(cy1 * W_ + cx0) * 16];
        u32 v11 = kg[(cy1 * W_ + cx1) * 16];

        float w00 = gx0 * gy0 * ((vx0 & vy0) ? 1.f : 0.f);
        float w01 = fx  * gy0 * ((vx1 & vy0) ? 1.f : 0.f);
        float w10 = gx0 * fy  * ((vx0 & vy1) ? 1.f : 0.f);
        float w11 = fx  * fy  * ((vx1 & vy1) ? 1.f : 0.f);

        a0 = fmaf(wt, w00 * bflo(v00) + w01 * bflo(v01) + w10 * bflo(v10) + w11 * bflo(v11), a0);
        a1 = fmaf(wt, w00 * bfhi(v00) + w01 * bfhi(v01) + w10 * bfhi(v10) + w11 * bfhi(v11), a1);
      }
      *(u32*)(smem + (kc * 64 + row) * 16 + word) = (u32)f2bf(a0) | ((u32)f2bf(a1) << 16);
    }
  }

  // ---- Phase 2: GEMM (64 x 256) = A(64x256) * w_proj^T(256x256) ----
  f32x4 acc[16];
  #pragma unroll
  for (int n = 0; n < 16; ++n) acc[n] = (f32x4){0.f, 0.f, 0.f, 0.f};

  for (int k0 = 0; k0 < 256; k0 += 32) {
    #pragma unroll
    for (int j = 0; j < 4; ++j) {
      int i = w * 4 + j;               // 0..15
      int kq = i >> 2, cg = i & 3;
      const u16* gsrc = Bw + ((size_t)(cg * 64 + l)) * 256 + k0 + kq * 8;
      __builtin_amdgcn_global_load_lds((const as1_u32*)gsrc,
          (as3_u32*)(smem + 32768 + (kq * 256 + cg * 64) * 16), 16, 0, 0);
    }
    __syncthreads();  // drains vmcnt; also guards phase-1 A writes on first pass

    const int kc = (k0 >> 3) + lq;
    bf16x8 af = *(const bf16x8*)(smem + (kc * 64 + w * 16 + lr) * 16);
    #pragma unroll
    for (int n = 0; n < 16; ++n) {
      bf16x8 bfr = *(const bf16x8*)(smem + 32768 + (lq * 256 + n * 16 + lr) * 16);
      acc[n] = __builtin_amdgcn_mfma_f32_16x16x32_bf16(af, bfr, acc[n], 0, 0, 0);
    }
    __syncthreads();  // before overwriting B chunk
  }

  // ---- epilogue ----
  #pragma unroll
  for (int n = 0; n < 16; ++n) {
    int col = n * 16 + lr;
    float bv = bias[col];
    int row = r0 + w * 16 + lq * 4;
    #pragma unroll
    for (int r = 0; r < 4; ++r)
      out[(size_t)(row + r) * 256 + col] = acc[n][r] + bv;
  }
}

// ---------------------------------------------------------------------------
extern "C" void kernel_launch(void* const* d_in, const int* in_sizes, int n_in,
                              void* d_out, int out_size, void* d_ws, size_t ws_size,
                              hipStream_t stream) {
  const float* query  = (const float*)d_in[0];
  const float* key    = (const float*)d_in[1];
  const float* w_off  = (const float*)d_in[2];
  const float* b_off  = (const float*)d_in[3];
  const float* w_proj = (const float*)d_in[4];
  const float* b_proj = (const float*)d_in[5];
  float* out = (float*)d_out;

  char* ws = (char*)d_ws;
  float4* params   = (float4*)ws;                               // 16 MB
  u32*    key_t2   = (u32*)(ws + (size_t)16 * 1024 * 1024);     // 16 MB
  uint2*  wproj_bf = (uint2*)(ws + (size_t)32 * 1024 * 1024);   // 128 KB

  hipLaunchKernelGGL(k_prep,  dim3(4416), dim3(256), 0, stream,
                     query, key, w_off, b_off, w_proj, params, key_t2, wproj_bf);
  hipLaunchKernelGGL(k_fused, dim3(512),  dim3(256), 0, stream,
                     params, key_t2, (const u16*)wproj_bf, b_proj, out);
}

// Round 6
// 88.771 us; speedup vs baseline: 2.9779x; 1.0376x over previous
//
#include <hip/hip_runtime.h>
#include <cstdint>

#define B_   8
#define C_   256
#define H_   64
#define W_   64
#define HW_  4096
#define NH_  8
#define NP_  4
#define DH_  32

typedef unsigned int u32;
typedef unsigned short u16;
typedef __attribute__((ext_vector_type(8))) short bf16x8;
typedef __attribute__((ext_vector_type(4))) float f32x4;
typedef __attribute__((ext_vector_type(4))) u32 u32x4;
typedef __attribute__((address_space(3))) u32 as3_u32;
typedef __attribute__((address_space(1))) u32 as1_u32;

__device__ __forceinline__ u16 f2bf(float f) {
  u32 u = __builtin_bit_cast(u32, f);
  return (u16)((u + 0x7FFFu + ((u >> 16) & 1u)) >> 16);
}
__device__ __forceinline__ float bflo(u32 v) { return __builtin_bit_cast(float, v << 16); }
__device__ __forceinline__ float bfhi(u32 v) { return __builtin_bit_cast(float, v & 0xFFFF0000u); }

// ---------------------------------------------------------------------------
// Kernel 1: merged prep (unchanged). blocks [0,4096): key transpose->bf16;
// [4096,4352): offsets MFMA GEMM + softmax -> params; [4352,4416): w_proj->bf16.
// ---------------------------------------------------------------------------
__global__ __launch_bounds__(256) void k_prep(const float* __restrict__ query,
                                              const float* __restrict__ key,
                                              const float* __restrict__ w_off,
                                              const float* __restrict__ b_off,
                                              const float* __restrict__ w_proj,
                                              float4* __restrict__ params,
                                              u32* __restrict__ key_t2,
                                              uint2* __restrict__ wproj_bf) {
  __shared__ char smem[57344];
  const int bid = blockIdx.x;
  const int t = threadIdx.x;

  if (bid < 4096) {
    float* tile = (float*)smem;  // 32 x 65
    const int g = bid >> 6;
    const int hw0 = (bid & 63) << 6;
    const float* kg = key + (size_t)g * DH_ * HW_ + hw0;
    #pragma unroll
    for (int k = 0; k < 8; ++k) {
      int idx = t + k * 256;
      int d = idx >> 6, j = idx & 63;
      tile[d * 65 + j] = kg[d * HW_ + j];
    }
    __syncthreads();
    u32* kt = key_t2 + ((size_t)g * HW_ + hw0) * 16;
    #pragma unroll
    for (int k = 0; k < 4; ++k) {
      int idx = t + k * 256;
      int j = idx >> 4, dp = idx & 15;
      u32 v = (u32)f2bf(tile[(2 * dp) * 65 + j]) | ((u32)f2bf(tile[(2 * dp + 1) * 65 + j]) << 16);
      kt[j * 16 + dp] = v;
    }
  } else if (bid < 4352) {
    const int l = t & 63, w = t >> 6;
    const int lr = l & 15, lq = l >> 4;
    const int r0 = (bid - 4096) * 128;
    const int b  = r0 >> 12;
    const int hw0 = r0 & 4095;

    {
      const float4* w4 = (const float4*)w_off;
      #pragma unroll
      for (int j = 0; j < 12; ++j) {
        int m = t + j * 256;
        int col = m >> 5, ch = m & 31;
        float4 lo = w4[m * 2];
        float4 hi = w4[m * 2 + 1];
        u32x4 v;
        v.x = (u32)f2bf(lo.x) | ((u32)f2bf(lo.y) << 16);
        v.y = (u32)f2bf(lo.z) | ((u32)f2bf(lo.w) << 16);
        v.z = (u32)f2bf(hi.x) | ((u32)f2bf(hi.y) << 16);
        v.w = (u32)f2bf(hi.z) | ((u32)f2bf(hi.w) << 16);
        int slot = (col << 5) | (ch ^ (col & 7));
        *(u32x4*)(smem + slot * 16) = v;
      }
    }

    f32x4 acc[2][6];
    #pragma unroll
    for (int m = 0; m < 2; ++m)
      #pragma unroll
      for (int n = 0; n < 6; ++n)
        acc[m][n] = (f32x4){0.f, 0.f, 0.f, 0.f};

    for (int step = 0; step < 8; ++step) {
      const int k0 = step * 32;
      #pragma unroll
      for (int it = 0; it < 8; ++it) {
        int idx = t + it * 256;
        int i = idx & 127;
        int p = idx >> 7;
        const float* src = query + ((size_t)(b * 256 + k0 + 2 * p)) * 4096 + hw0 + i;
        u32 v = (u32)f2bf(src[0]) | ((u32)f2bf(src[4096]) << 16);
        *(u32*)(smem + 49152 + ((p >> 2) * 128 + i) * 16 + (p & 3) * 4) = v;
      }
      __syncthreads();

      const int chb = step * 4 + lq;
      bf16x8 bfr[6], af[2];
      #pragma unroll
      for (int n = 0; n < 6; ++n) {
        int col = n * 16 + lr;
        bfr[n] = *(const bf16x8*)(smem + ((col << 5) | (chb ^ (col & 7))) * 16);
      }
      #pragma unroll
      for (int m = 0; m < 2; ++m)
        af[m] = *(const bf16x8*)(smem + 49152 + (lq * 128 + w * 32 + m * 16 + lr) * 16);

      #pragma unroll
      for (int m = 0; m < 2; ++m)
        #pragma unroll
        for (int n = 0; n < 6; ++n)
          acc[m][n] = __builtin_amdgcn_mfma_f32_16x16x32_bf16(af[m], bfr[n], acc[m][n], 0, 0, 0);
      __syncthreads();
    }

    float* epi = (float*)smem;
    #pragma unroll
    for (int n = 0; n < 6; ++n) {
      int o = n * 16 + lr;
      float bo = b_off[o];
      #pragma unroll
      for (int m = 0; m < 2; ++m) {
        int row = w * 32 + m * 16 + lq * 4;
        #pragma unroll
        for (int r = 0; r < 4; ++r)
          epi[(row + r) * 98 + o] = acc[m][n][r] + bo;
      }
    }
    __syncthreads();

    #pragma unroll
    for (int k = 0; k < 4; ++k) {
      int task = t + k * 256;
      int row = task & 127, head = task >> 7;
      const float* o = epi + row * 98 + head * 12;
      float ox[NP_], oy[NP_], lg[NP_];
      #pragma unroll
      for (int p = 0; p < NP_; ++p) {
        ox[p] = o[p * 3 + 0];
        oy[p] = o[p * 3 + 1];
        lg[p] = o[p * 3 + 2];
      }
      float mx = fmaxf(fmaxf(lg[0], lg[1]), fmaxf(lg[2], lg[3]));
      float e[NP_];
      float s = 0.f;
      #pragma unroll
      for (int p = 0; p < NP_; ++p) { e[p] = expf(lg[p] - mx); s += e[p]; }
      float inv = 1.f / s;

      int hw = (r0 + row) & 4095;
      float wq = (float)(hw & 63);
      float hq = (float)(hw >> 6);
      float4* dst = params + ((size_t)(b * NH_ + head) * HW_ + hw) * NP_;
      #pragma unroll
      for (int p = 0; p < NP_; ++p) {
        dst[p] = make_float4(wq + ox[p] * 3.15f, hq + oy[p] * 3.15f, e[p] * inv, 0.f);
      }
    }
  } else {
    int i = (bid - 4352) * 256 + t;
    float4 v = ((const float4*)w_proj)[i];
    uint2 o;
    o.x = (u32)f2bf(v.x) | ((u32)f2bf(v.y) << 16);
    o.y = (u32)f2bf(v.z) | ((u32)f2bf(v.w) << 16);
    wproj_bf[i] = o;
  }
}

// ---------------------------------------------------------------------------
// Kernel 2: fused sample + projection, 32-row tiles (1024 blocks, 4 blocks/CU).
// Phase 1: bilinear-sample into LDS A layout [kc 0..31][row 0..31] 16B slots,
//   validated dp-lane mapping (consecutive lanes -> 64B coalesced gathers).
// Phase 2: GEMM 32x256x256: wave = (Mtile wm, N-half wn), 8 MFMA per chunk.
// ---------------------------------------------------------------------------
__global__ __launch_bounds__(256) void k_fused(const float4* __restrict__ params,
                                               const u32* __restrict__ key_t2,
                                               const u16* __restrict__ Bw,
                                               const float* __restrict__ bias,
                                               float* __restrict__ out) {
  __shared__ char smem[32768];  // A: [0,16K)  B-chunk: [16K,32K)
  const int t = threadIdx.x, l = t & 63, w = t >> 6;
  const int lr = l & 15, lq = l >> 4;
  const int wm = w & 1, wn = w >> 1;
  const int r0 = blockIdx.x * 32;
  const int b = r0 >> 12;
  const int hw0 = r0 & 4095;

  // ---- Phase 1: sampling ----
  {
    const int dp   = t & 15;
    const int head = (t >> 4) & 7;
    const int rsub = t >> 7;           // 0..1
    const int g = b * NH_ + head;
    const u32* kg = key_t2 + ((size_t)g << 16) + dp;
    const int kc = head * 4 + (dp >> 2);
    const int word = (dp & 3) * 4;

    #pragma unroll 4
    for (int it = 0; it < 16; ++it) {
      int row = it * 2 + rsub;
      int hw = hw0 + row;
      const float4* pp = params + (((size_t)g << 12) + hw) * NP_;

      float a0 = 0.f, a1 = 0.f;
      #pragma unroll
      for (int p = 0; p < NP_; ++p) {
        float4 pr = pp[p];
        float x = pr.x, y = pr.y, wt = pr.z;
        float x0f = floorf(x), y0f = floorf(y);
        int ix0 = (int)x0f, iy0 = (int)y0f;
        int ix1 = ix0 + 1, iy1 = iy0 + 1;
        float fx = x - x0f, fy = y - y0f;
        float gx0 = 1.f - fx, gy0 = 1.f - fy;

        bool vx0 = (ix0 >= 0) & (ix0 <= W_ - 1);
        bool vx1 = (ix1 >= 0) & (ix1 <= W_ - 1);
        bool vy0 = (iy0 >= 0) & (iy0 <= H_ - 1);
        bool vy1 = (iy1 >= 0) & (iy1 <= H_ - 1);
        int cx0 = min(max(ix0, 0), W_ - 1), cx1 = min(max(ix1, 0), W_ - 1);
        int cy0 = min(max(iy0, 0), H_ - 1), cy1 = min(max(iy1, 0), H_ - 1);

        u32 v00 = kg[(cy0 * W_ + cx0) * 16];
        u32 v01 = kg[(cy0 * W_ + cx1) * 16];
        u32 v10 = kg[(cy1 * W_ + cx0) * 16];
        u32 v11 = kg[(cy1 * W_ + cx1) * 16];

        float w00 = gx0 * gy0 * ((vx0 & vy0) ? 1.f : 0.f);
        float w01 = fx  * gy0 * ((vx1 & vy0) ? 1.f : 0.f);
        float w10 = gx0 * fy  * ((vx0 & vy1) ? 1.f : 0.f);
        float w11 = fx  * fy  * ((vx1 & vy1) ? 1.f : 0.f);

        a0 = fmaf(wt, w00 * bflo(v00) + w01 * bflo(v01) + w10 * bflo(v10) + w11 * bflo(v11), a0);
        a1 = fmaf(wt, w00 * bfhi(v00) + w01 * bfhi(v01) + w10 * bfhi(v10) + w11 * bfhi(v11), a1);
      }
      *(u32*)(smem + (kc * 32 + row) * 16 + word) = (u32)f2bf(a0) | ((u32)f2bf(a1) << 16);
    }
  }

  // ---- Phase 2: GEMM (32 x 256) = A(32x256) * w_proj^T(256x256) ----
  f32x4 acc[8];
  #pragma unroll
  for (int n = 0; n < 8; ++n) acc[n] = (f32x4){0.f, 0.f, 0.f, 0.f};

  for (int k0 = 0; k0 < 256; k0 += 32) {
    // stage B chunk: slots [kq 0..3][col 0..255], 16 x 1KB issues, 4/wave
    #pragma unroll
    for (int j = 0; j < 4; ++j) {
      int i = w * 4 + j;               // 0..15
      int kq = i >> 2, cg = i & 3;
      const u16* gsrc = Bw + ((size_t)(cg * 64 + l)) * 256 + k0 + kq * 8;
      __builtin_amdgcn_global_load_lds((const as1_u32*)gsrc,
          (as3_u32*)(smem + 16384 + (kq * 256 + cg * 64) * 16), 16, 0, 0);
    }
    __syncthreads();  // drains vmcnt; also guards phase-1 A writes on first pass

    const int kc = (k0 >> 3) + lq;
    bf16x8 af = *(const bf16x8*)(smem + (kc * 32 + wm * 16 + lr) * 16);
    #pragma unroll
    for (int n = 0; n < 8; ++n) {
      bf16x8 bfr = *(const bf16x8*)(smem + 16384 + (lq * 256 + wn * 128 + n * 16 + lr) * 16);
      acc[n] = __builtin_amdgcn_mfma_f32_16x16x32_bf16(af, bfr, acc[n], 0, 0, 0);
    }
    __syncthreads();  // before overwriting B chunk
  }

  // ---- epilogue ----
  #pragma unroll
  for (int n = 0; n < 8; ++n) {
    int col = wn * 128 + n * 16 + lr;
    float bv = bias[col];
    int row = r0 + wm * 16 + lq * 4;
    #pragma unroll
    for (int r = 0; r < 4; ++r)
      out[(size_t)(row + r) * 256 + col] = acc[n][r] + bv;
  }
}

// ---------------------------------------------------------------------------
extern "C" void kernel_launch(void* const* d_in, const int* in_sizes, int n_in,
                              void* d_out, int out_size, void* d_ws, size_t ws_size,
                              hipStream_t stream) {
  const float* query  = (const float*)d_in[0];
  const float* key    = (const float*)d_in[1];
  const float* w_off  = (const float*)d_in[2];
  const float* b_off  = (const float*)d_in[3];
  const float* w_proj = (const float*)d_in[4];
  const float* b_proj = (const float*)d_in[5];
  float* out = (float*)d_out;

  char* ws = (char*)d_ws;
  float4* params   = (float4*)ws;                               // 16 MB
  u32*    key_t2   = (u32*)(ws + (size_t)16 * 1024 * 1024);     // 16 MB
  uint2*  wproj_bf = (uint2*)(ws + (size_t)32 * 1024 * 1024);   // 128 KB

  hipLaunchKernelGGL(k_prep,  dim3(4416), dim3(256), 0, stream,
                     query, key, w_off, b_off, w_proj, params, key_t2, wproj_bf);
  hipLaunchKernelGGL(k_fused, dim3(1024), dim3(256), 0, stream,
                     params, key_t2, (const u16*)wproj_bf, b_proj, out);
}